// Round 2
// baseline (1008.321 us; speedup 1.0000x reference)
//
#include <hip/hip_runtime.h>
#include <cfloat>

#define LATENT 256
#define NV 8192
#define NROWS 16384   // B*H*W
#define HW 1024
#define CHW (LATENT * HW)         // 262144
#define PLANE 4194304             // B*C*H*W
#define IDX_OFF (2 * PLANE)       // 8388608
#define LOSS_OFF (IDX_OFF + NROWS)

// ---------------- kernel 1: fused distance + argmin ----------------
// Matches numpy/jax fp32 semantics: d = fp32(X_i - 2*dot_ik) where
// X_i = fp32(||x_i||^2) (any fp32 in the binade — bucket structure invariant),
// dot accumulated as a k-ascending fp32 FMA chain (BLAS microkernel order).
// ||e_k||^2 provably vanishes in fp32 rounding (< half-ulp of X_i).
// Argmin tie rule: first (smallest) index among equal fp32 d values.
// grid 256: (row-block 0..127) x (code-split 0..1). 512 threads.
__global__ __launch_bounds__(512) void dist_argmin(
    const float* __restrict__ x, const float* __restrict__ ek,
    float* __restrict__ pval, int* __restrict__ pidx) {
  __shared__ float xs[256][128];   // xs[c][r]
  __shared__ float es[32][132];    // es[c][k], padded stride
  __shared__ float Xr[128];        // ||x||^2 per row
  const int t = threadIdx.x;
  const int rb = blockIdx.x & 127;
  const int ns = blockIdx.x >> 7;
  const int i0 = rb << 7;
  const int b = i0 >> 10;
  const int hw0 = i0 & 1023;
  const float* xb = x + (size_t)b * CHW + hw0;
  // stage x: 256c x 128r, coalesced along r, transposed into LDS
  for (int p = 0; p < 16; ++p) {
    int id = (p << 9) + t;
    int c = id >> 5;
    int r = (id & 31) << 2;
    float4 v = *(const float4*)(xb + c * HW + r);
    *(float4*)&xs[c][r] = v;
  }
  __syncthreads();
  if (t < 128) {  // row norms, f64 accumulate -> 0.5-ulp fp32 value
    double s = 0.0;
    for (int c = 0; c < 256; ++c) {
      double v = (double)xs[c][t];
      s = fma(v, v, s);
    }
    Xr[t] = (float)s;
  }
  __syncthreads();
  const int ty = t >> 5;  // 0..15 -> rows ty*8
  const int tx = t & 31;  // codes tx*4
  float xrow[8];
  #pragma unroll
  for (int r = 0; r < 8; ++r) xrow[r] = Xr[(ty << 3) + r];
  float mval[8];
  int midx[8];
  #pragma unroll
  for (int r = 0; r < 8; ++r) { mval[r] = FLT_MAX; midx[r] = 0; }
  const int kbase = ns << 12;
  for (int nc = 0; nc < 32; ++nc) {
    const int k0 = kbase + (nc << 7);
    float acc[8][4];
    #pragma unroll
    for (int r = 0; r < 8; ++r)
      #pragma unroll
      for (int j = 0; j < 4; ++j) acc[r][j] = 0.f;
    for (int cc = 0; cc < 8; ++cc) {
      __syncthreads();
      {  // stage 128 codes x 32 c, transposed
        int kl = t >> 2;
        int cl = (t & 3) << 3;
        const float* eb = ek + (size_t)(k0 + kl) * LATENT + (cc << 5) + cl;
        float4 v0 = *(const float4*)eb;
        float4 v1 = *(const float4*)(eb + 4);
        es[cl + 0][kl] = v0.x; es[cl + 1][kl] = v0.y;
        es[cl + 2][kl] = v0.z; es[cl + 3][kl] = v0.w;
        es[cl + 4][kl] = v1.x; es[cl + 5][kl] = v1.y;
        es[cl + 6][kl] = v1.z; es[cl + 7][kl] = v1.w;
      }
      __syncthreads();
      const int cb = cc << 5;
      #pragma unroll
      for (int c = 0; c < 32; ++c) {  // c ascending 0..255 across cc: BLAS order
        float a[8], bv[4];
        *(float4*)&a[0] = *(const float4*)&xs[cb + c][ty << 3];
        *(float4*)&a[4] = *(const float4*)&xs[cb + c][(ty << 3) + 4];
        *(float4*)&bv[0] = *(const float4*)&es[c][tx << 2];
        #pragma unroll
        for (int r = 0; r < 8; ++r)
          #pragma unroll
          for (int j = 0; j < 4; ++j) acc[r][j] = fmaf(a[r], bv[j], acc[r][j]);
      }
    }
    // d = fp32(X - 2*dot); 2*acc exact => fused or unfused identical
    #pragma unroll
    for (int j = 0; j < 4; ++j) {
      int k = k0 + (tx << 2) + j;
      #pragma unroll
      for (int r = 0; r < 8; ++r) {
        float d = fmaf(-2.0f, acc[r][j], xrow[r]);
        if (d < mval[r]) { mval[r] = d; midx[r] = k; }  // strict <: first index wins
      }
    }
  }
  __syncthreads();
  float* rv = &xs[0][0];          // [128][32] vals
  int* ri = (int*)&xs[64][0];     // [128][32] idxs (disjoint region)
  #pragma unroll
  for (int r = 0; r < 8; ++r) {
    int row = (ty << 3) + r;
    rv[(row << 5) + tx] = mval[r];
    ri[(row << 5) + tx] = midx[r];
  }
  __syncthreads();
  if (t < 128) {
    float bv = rv[t << 5];
    int bi = ri[t << 5];
    for (int j = 1; j < 32; ++j) {
      float v = rv[(t << 5) + j];
      int ii = ri[(t << 5) + j];
      if (v < bv || (v == bv && ii < bi)) { bv = v; bi = ii; }
    }
    pval[((i0 + t) << 1) + ns] = bv;
    pidx[((i0 + t) << 1) + ns] = bi;
  }
}

// ---------------- kernel 2: merge idx, gather-GEMM, outputs ----------------
__global__ __launch_bounds__(256) void out_kernel(
    const float* __restrict__ ek, const float* __restrict__ ev,
    const float* __restrict__ x, const float* __restrict__ pval,
    const int* __restrict__ pidx, float* __restrict__ out,
    float* __restrict__ bsum) {
  __shared__ float As[32][68];    // gathered ek chunk, [c][row]
  __shared__ float Vs[32][260];   // V chunk, [c][j]
  __shared__ int idx_s[64];
  __shared__ float red[256];
  const int t = threadIdx.x;
  const int blk = blockIdx.x;
  const int i0 = blk << 6;
  if (t < 64) {
    int i = i0 + t;
    float v0 = pval[i << 1], v1 = pval[(i << 1) + 1];
    int j0 = pidx[i << 1], j1 = pidx[(i << 1) + 1];
    int id = (v1 < v0) ? j1 : j0;  // tie -> split 0 (smaller index)
    idx_s[t] = id;
    out[IDX_OFF + i] = (float)id;
  }
  const int ty = t >> 5;  // rows ty*8 (of 64)
  const int tx = t & 31;  // j = tx*8 (of 256)
  float acc[8][8];
  #pragma unroll
  for (int r = 0; r < 8; ++r)
    #pragma unroll
    for (int j = 0; j < 8; ++j) acc[r][j] = 0.f;
  for (int cc = 0; cc < 8; ++cc) {
    __syncthreads();
    {  // gather A chunk: 64 rows x 32 c, transposed
      int r = t >> 2, cl = (t & 3) << 3;
      const float* eb = ek + (size_t)idx_s[r] * LATENT + (cc << 5) + cl;
      float4 v0 = *(const float4*)eb;
      float4 v1 = *(const float4*)(eb + 4);
      As[cl + 0][r] = v0.x; As[cl + 1][r] = v0.y;
      As[cl + 2][r] = v0.z; As[cl + 3][r] = v0.w;
      As[cl + 4][r] = v1.x; As[cl + 5][r] = v1.y;
      As[cl + 6][r] = v1.z; As[cl + 7][r] = v1.w;
    }
    {  // stage V chunk: 32 c x 256 j
      int c = t >> 3, jb = (t & 7) << 5;
      const float* vb = ev + (size_t)((cc << 5) + c) * LATENT + jb;
      float4* dst = (float4*)&Vs[c][jb];
      #pragma unroll
      for (int q = 0; q < 8; ++q) dst[q] = *(const float4*)(vb + 4 * q);
    }
    __syncthreads();
    #pragma unroll
    for (int c = 0; c < 32; ++c) {
      float a[8], bv[8];
      *(float4*)&a[0] = *(const float4*)&As[c][ty << 3];
      *(float4*)&a[4] = *(const float4*)&As[c][(ty << 3) + 4];
      *(float4*)&bv[0] = *(const float4*)&Vs[c][tx << 3];
      *(float4*)&bv[4] = *(const float4*)&Vs[c][(tx << 3) + 4];
      #pragma unroll
      for (int r = 0; r < 8; ++r)
        #pragma unroll
        for (int j = 0; j < 8; ++j) acc[r][j] = fmaf(a[r], bv[j], acc[r][j]);
    }
  }
  // epilogue: transpose to (b,c,h,w); xq_st = xt + (xq - xt); xq_grad = xq
  const int bb = i0 >> 10;
  const int rbase = (i0 & 1023) + (ty << 3);
  float lsum = 0.f;
  #pragma unroll
  for (int j = 0; j < 8; ++j) {
    int jc = (tx << 3) + j;
    const float* xp = x + (size_t)bb * CHW + (size_t)jc * HW + rbase;
    float* o0 = out + (size_t)bb * CHW + (size_t)jc * HW + rbase;
    float* o1 = o0 + PLANE;
    float st[8], xq0[8];
    #pragma unroll
    for (int r = 0; r < 8; ++r) {
      float xq = acc[r][j];
      float xt = xp[r];
      float tmp = xq - xt;
      lsum = fmaf(tmp, tmp, lsum);
      st[r] = xt + tmp;
      xq0[r] = xq;
    }
    *(float4*)(o0 + 0) = make_float4(st[0], st[1], st[2], st[3]);
    *(float4*)(o0 + 4) = make_float4(st[4], st[5], st[6], st[7]);
    *(float4*)(o1 + 0) = make_float4(xq0[0], xq0[1], xq0[2], xq0[3]);
    *(float4*)(o1 + 4) = make_float4(xq0[4], xq0[5], xq0[6], xq0[7]);
  }
  red[t] = lsum;
  __syncthreads();
  for (int s = 128; s > 0; s >>= 1) {
    if (t < s) red[t] += red[t + s];
    __syncthreads();
  }
  if (t == 0) bsum[blk] = red[0];
}

// ---------------- kernel 3: loss ----------------
__global__ __launch_bounds__(256) void fin_kernel(const float* __restrict__ bsum,
                                                  float* __restrict__ out) {
  __shared__ float red[256];
  int t = threadIdx.x;
  red[t] = bsum[t];
  __syncthreads();
  for (int s = 128; s > 0; s >>= 1) {
    if (t < s) red[t] += red[t + s];
    __syncthreads();
  }
  if (t == 0) {
    float m = red[0] / (float)PLANE;
    out[LOSS_OFF] = m + 0.25f * m;
  }
}

extern "C" void kernel_launch(void* const* d_in, const int* in_sizes, int n_in,
                              void* d_out, int out_size, void* d_ws, size_t ws_size,
                              hipStream_t stream) {
  const float* x = (const float*)d_in[0];
  const float* ek = (const float*)d_in[1];
  const float* ev = (const float*)d_in[2];
  float* out = (float*)d_out;
  float* ws = (float*)d_ws;
  float* pval = ws;                                // 32768
  int* pidx = (int*)(ws + 2 * NROWS);              // 32768
  float* bsum = ws + 4 * NROWS;                    // 256

  dist_argmin<<<256, 512, 0, stream>>>(x, ek, pval, pidx);
  out_kernel<<<256, 256, 0, stream>>>(ek, ev, x, pval, pidx, out, bsum);
  fin_kernel<<<1, 256, 0, stream>>>(bsum, out);
}